// Round 15
// baseline (107.879 us; speedup 1.0000x reference)
//
#include <hip/hip_runtime.h>
#include <hip/hip_fp16.h>
#include <math.h>

typedef _Float16 f16x8 __attribute__((ext_vector_type(8)));
typedef _Float16 f16x4 __attribute__((ext_vector_type(4)));
typedef float f32x4 __attribute__((ext_vector_type(4)));

#define DD     128     // d
#define D2     256     // 2d
#define NB     8192    // batch
#define NCLS   5
#define KSPLIT 8
#define BM     96      // 96-row tile -> LDS 49.5 KB -> 3 blocks/CU (12 waves, 3/SIMD)
#define NMT    86      // ceil(8192/96)
#define PPAD   258     // row stride 516B = 129 dw == 1 mod 32 -> conflict-free
#define NSB    36      // 8x8 block-triangle: 28 off-diag (V+V^T) + 8 diag (raw V)
#define SB_BYTES  262144u              // 128 granules * 128 n * 16 B
#define TAIL_OFF  (36u * 262144u)      // W_w tail after all superblocks
#define PART_OFF  (10u * 1048576u)     // fp32 partials at +10 MB

// ---- prep: build symmetrized Vt fp16 in MFMA fragment layout ----------------------------
__global__ void prep_vt(const float* __restrict__ V, const float* __restrict__ Ww,
                        _Float16* __restrict__ Vt) {
    int t = blockIdx.x * 256 + threadIdx.x;      // thread per (granule-unit, n)
    int u = t >> 7;
    int n = t & 127;
    f16x8 v;
    if (u < NSB * 128) {
        int s = u >> 7, g = u & 127;
        int bi = 0, rem = s;
        while (rem >= 8 - bi) { rem -= 8 - bi; ++bi; }
        int bj = bi + rem;
        int i  = bi * 32 + (g >> 2);
        int j0 = bj * 32 + (g & 3) * 8;
        if (bi == bj) {
            #pragma unroll
            for (int e = 0; e < 8; ++e)
                v[e] = (_Float16)V[((size_t)i * 256 + j0 + e) * 128 + n];
        } else {
            #pragma unroll
            for (int e = 0; e < 8; ++e)
                v[e] = (_Float16)(V[((size_t)i * 256 + j0 + e) * 128 + n]
                                + V[((size_t)(j0 + e) * 256 + i) * 128 + n]);
        }
    } else {
        int g = u - NSB * 128;                   // 0..31
        int j0 = g * 8;
        #pragma unroll
        for (int e = 0; e < 8; ++e)
            v[e] = (_Float16)Ww[n * D2 + j0 + e];
    }
    *(f16x8*)(Vt + (size_t)u * 1024 + n * 8) = v;
}

// ---------------- main: tp_partial[ks][b][k] via outer-product-A MFMA GEMM ----------------
// 2x2 wave grid, wave tile 48x64 (mr=3, nr=4). 12 MFMA per 4-load cluster.
// Inline-asm B-loads, dataflow-carried counted vmcnt (R14 structure, verified).
__global__ __launch_bounds__(256, 3) void gemm_bilinear(
        const float* __restrict__ left, const float* __restrict__ right,
        const _Float16* __restrict__ Vt, float* __restrict__ part) {
    __shared__ _Float16 P[BM][PPAD];

    const int bid = blockIdx.x;
    const int ks  = bid & 7;       // == XCD id under round-robin dispatch -> slice per XCD L2
    const int m0  = (bid >> 3) * BM;
    const int tid = threadIdx.x;

    // stage phrase tile (fp32 global -> fp16 LDS); tail mtile rows clamp to 8191
    for (int it = 0; it < 24; ++it) {
        int f4  = it * 256 + tid;          // float4 index over [96][256]
        int row = f4 >> 6;
        int col = (f4 & 63) * 4;
        int grow = m0 + row; if (grow > NB - 1) grow = NB - 1;
        const float* src = (col < DD) ? (left  + (size_t)grow * DD + col)
                                      : (right + (size_t)grow * DD + (col - DD));
        float4 x = *(const float4*)src;
        f16x4 hv;
        hv[0] = (_Float16)x.x; hv[1] = (_Float16)x.y;
        hv[2] = (_Float16)x.z; hv[3] = (_Float16)x.w;
        *(f16x4*)&P[row][col] = hv;
    }
    __syncthreads();

    const int lane = tid & 63;
    const int wid  = tid >> 6;
    const int wm   = wid >> 1, wn = wid & 1;   // 2x2 wave grid, 48x64 wave tile
    const int l15  = lane & 15, lg = lane >> 4;
    const int rowb = wm * 48;
    const int coln = wn * 64;

    f32x4 acc[3][4];
    #pragma unroll
    for (int u = 0; u < 3; ++u)
        #pragma unroll
        for (int w = 0; w < 4; ++w)
            acc[u][w] = (f32x4){0.f, 0.f, 0.f, 0.f};

    const unsigned lane_nbyte = (unsigned)((coln + l15) * 16);
    #define LDV(off) (*(const f16x8*)((const char*)Vt + (off)))

    // inline-asm B-load: 4 x dwordx4, saddr form + imm offsets. Pinned issue order.
    #define LOADB(BUF)                                                                    \
        asm volatile("global_load_dwordx4 %0, %4, %5\n\t"                                 \
                     "global_load_dwordx4 %1, %4, %5 offset:256\n\t"                      \
                     "global_load_dwordx4 %2, %4, %5 offset:512\n\t"                      \
                     "global_load_dwordx4 %3, %4, %5 offset:768"                          \
            : "=&v"(BUF[0]), "=&v"(BUF[1]), "=&v"(BUF[2]), "=&v"(BUF[3])                  \
            : "v"(voff), "s"(Vt));                                                        \
        voff += 8192u;

    // counted wait that DEFINES the buffer it guards (dataflow-ordered, nothing else fenced)
    #define WAITN(N, BUF)                                                                 \
        asm volatile("s_waitcnt vmcnt(" #N ")"                                            \
            : "+v"(BUF[0]), "+v"(BUF[1]), "+v"(BUF[2]), "+v"(BUF[3]));

    #define MFMA_CLUSTER(BUF, IBE)                                                        \
        _Pragma("unroll")                                                                 \
        for (int mr = 0; mr < 3; ++mr) {                                                  \
            const _Float16 sc = pis[mr][IBE];                                             \
            const f16x8 a = pj[mr] * sc;                                                  \
            _Pragma("unroll")                                                             \
            for (int nr = 0; nr < 4; ++nr)                                                \
                acc[mr][nr] = __builtin_amdgcn_mfma_f32_16x16x32_f16(a, BUF[nr], acc[mr][nr], 0, 0, 0); \
        }

    #define LOAD_PIS(IBC)                                                                 \
        f16x8 pis[3];                                                                     \
        _Pragma("unroll")                                                                 \
        for (int mr = 0; mr < 3; ++mr)                                                    \
            pis[mr] = *(const f16x8*)&P[rowb + mr * 16 + l15][bi * 32 + (IBC) * 8];

    #pragma unroll 1
    for (int si = 0; si < 5; ++si) {
        int s, ibcS, ibcE;
        if (si < 4) { s = ks * 4 + si;      ibcS = 0;            ibcE = 4; }
        else        { s = 32 + (ks >> 1);   ibcS = (ks & 1) * 2; ibcE = ibcS + 2; }

        // decode (bi, bj) from triangle slot (wave-uniform scalar loop)
        int bi = 0, rem = s;
        while (rem >= 8 - bi) { rem -= 8 - bi; ++bi; }
        const int bj = bi + rem;

        // A j-fragments for this superblock (invariant over i)
        f16x8 pj[3];
        #pragma unroll
        for (int mr = 0; mr < 3; ++mr)
            pj[mr] = *(const f16x8*)&P[rowb + mr * 16 + l15][bj * 32 + lg * 8];

        unsigned voff = lane_nbyte + (unsigned)s * SB_BYTES + (unsigned)(lg * 2048)
                      + (unsigned)(ibcS * 65536);

        // prologue: fill pipeline to depth 2 (clusters 0,1)
        f16x8 B0[4], B1[4], B2[4], B3[4];
        LOADB(B0)
        LOADB(B1)

        // steady ibcs (all but the last of this superblock)
        #pragma unroll 1
        for (int ibc = ibcS; ibc < ibcE - 1; ++ibc) {
            LOAD_PIS(ibc)
            LOADB(B2)  WAITN(8, B0)  MFMA_CLUSTER(B0, 0)
            LOADB(B3)  WAITN(8, B1)  MFMA_CLUSTER(B1, 1)
            LOADB(B0)  WAITN(8, B2)  MFMA_CLUSTER(B2, 2)
            LOADB(B1)  WAITN(8, B3)  MFMA_CLUSTER(B3, 3)
            LOADB(B2)  WAITN(8, B0)  MFMA_CLUSTER(B0, 4)
            LOADB(B3)  WAITN(8, B1)  MFMA_CLUSTER(B1, 5)
            LOADB(B0)  WAITN(8, B2)  MFMA_CLUSTER(B2, 6)
            LOADB(B1)  WAITN(8, B3)  MFMA_CLUSTER(B3, 7)
        }

        // final ibc: steps 0-5 still prefetch in-superblock; 6,7 drain. Every def consumed.
        {
            LOAD_PIS(ibcE - 1)
            LOADB(B2)  WAITN(8, B0)  MFMA_CLUSTER(B0, 0)
            LOADB(B3)  WAITN(8, B1)  MFMA_CLUSTER(B1, 1)
            LOADB(B0)  WAITN(8, B2)  MFMA_CLUSTER(B2, 2)
            LOADB(B1)  WAITN(8, B3)  MFMA_CLUSTER(B3, 3)
            LOADB(B2)  WAITN(8, B0)  MFMA_CLUSTER(B0, 4)
            LOADB(B3)  WAITN(8, B1)  MFMA_CLUSTER(B1, 5)
                       WAITN(4, B2)  MFMA_CLUSTER(B2, 6)
                       WAITN(0, B3)  MFMA_CLUSTER(B3, 7)
        }
    }

    // last split also does the folded W_w matvec tail: A = P directly
    if (ks == KSPLIT - 1) {
        #pragma unroll 1
        for (int jc = 0; jc < 8; ++jc) {
            unsigned voff = TAIL_OFF + (unsigned)((jc * 4 + lg) * 2048) + lane_nbyte;
            f16x8 bfr[4];
            #pragma unroll
            for (int nr = 0; nr < 4; ++nr) bfr[nr] = LDV(voff + nr * 256);
            #pragma unroll
            for (int mr = 0; mr < 3; ++mr) {
                const f16x8 a = *(const f16x8*)&P[rowb + mr * 16 + l15][jc * 32 + lg * 8];
                #pragma unroll
                for (int nr = 0; nr < 4; ++nr)
                    acc[mr][nr] = __builtin_amdgcn_mfma_f32_16x16x32_f16(a, bfr[nr], acc[mr][nr], 0, 0, 0);
            }
        }
    }

    // write fp32 partials; C/D layout: col = lane&15, row = (lane>>4)*4 + q  [m89-verified]
    // tail mtile: guard rows >= NB
    float* base = part + (size_t)ks * NB * DD;
    #pragma unroll
    for (int mr = 0; mr < 3; ++mr)
        #pragma unroll
        for (int nr = 0; nr < 4; ++nr) {
            const int col = coln + nr * 16 + l15;
            #pragma unroll
            for (int q = 0; q < 4; ++q) {
                const int row = m0 + rowb + mr * 16 + lg * 4 + q;
                if (row < NB)
                    base[(size_t)row * DD + col] = acc[mr][nr][q];
            }
        }
}

// ---------------- epilogue: reduce splits, +W_b, tanh, 5-class logits, log_softmax --------
// 8 threads per batch row (k-split 16 each) + shuffle reduce
__global__ void finish(const float* __restrict__ part, const float* __restrict__ Wb,
                       const float* __restrict__ Wsw, const float* __restrict__ Wsb,
                       float* __restrict__ out) {
    int t  = blockIdx.x * 256 + threadIdx.x;
    int b  = t >> 3;
    int kq = t & 7;                 // k-eighth
    if (b >= NB) return;
    float lg[NCLS];
    #pragma unroll
    for (int c = 0; c < NCLS; ++c) lg[c] = 0.f;

    const float* pb = part + (size_t)b * DD + kq * 16;
    #pragma unroll 1
    for (int k4 = 0; k4 < 4; ++k4) {
        float4 tt = *(const float4*)(Wb + kq * 16 + k4 * 4);
        #pragma unroll
        for (int s = 0; s < KSPLIT; ++s) {
            float4 p = *(const float4*)(pb + (size_t)s * NB * DD + k4 * 4);
            tt.x += p.x; tt.y += p.y; tt.z += p.z; tt.w += p.w;
        }
        float tq[4] = {tt.x, tt.y, tt.z, tt.w};
        #pragma unroll
        for (int q = 0; q < 4; ++q) {
            float h = tanhf(tq[q]);
            int k = kq * 16 + k4 * 4 + q;
            #pragma unroll
            for (int c = 0; c < NCLS; ++c)
                lg[c] += h * Wsw[c * DD + k];
        }
    }
    // reduce across the 8 k-eighth lanes (lane bits 0..2)
    #pragma unroll
    for (int c = 0; c < NCLS; ++c) {
        lg[c] += __shfl_xor(lg[c], 1);
        lg[c] += __shfl_xor(lg[c], 2);
        lg[c] += __shfl_xor(lg[c], 4);
    }
    if (kq == 0) {
        #pragma unroll
        for (int c = 0; c < NCLS; ++c) lg[c] += Wsb[c];
        float mx = lg[0];
        #pragma unroll
        for (int c = 1; c < NCLS; ++c) mx = fmaxf(mx, lg[c]);
        float sum = 0.f;
        #pragma unroll
        for (int c = 0; c < NCLS; ++c) sum += expf(lg[c] - mx);
        float lse = logf(sum);
        #pragma unroll
        for (int c = 0; c < NCLS; ++c) out[b * NCLS + c] = lg[c] - mx - lse;
    }
}

extern "C" void kernel_launch(void* const* d_in, const int* in_sizes, int n_in,
                              void* d_out, int out_size, void* d_ws, size_t ws_size,
                              hipStream_t stream) {
    const float* left  = (const float*)d_in[0];
    const float* right = (const float*)d_in[1];
    const float* V     = (const float*)d_in[2];
    const float* Ww    = (const float*)d_in[3];
    const float* Wb    = (const float*)d_in[4];
    const float* Wsw   = (const float*)d_in[5];
    const float* Wsb   = (const float*)d_in[6];
    float* out = (float*)d_out;

    _Float16* Vt = (_Float16*)d_ws;                       // 9,502,720 B incl. tail
    float* part  = (float*)((char*)d_ws + PART_OFF);      // 33,554,432 B

    hipLaunchKernelGGL(prep_vt, dim3(2320), dim3(256), 0, stream, V, Ww, Vt);
    hipLaunchKernelGGL(gemm_bilinear, dim3(NMT * KSPLIT), dim3(256), 0, stream,
                       left, right, Vt, part);
    hipLaunchKernelGGL(finish, dim3(NB * 8 / 256), dim3(256), 0, stream, part, Wb, Wsw, Wsb, out);
}

// Round 16
// 98.258 us; speedup vs baseline: 1.0979x; 1.0979x over previous
//
#include <hip/hip_runtime.h>
#include <hip/hip_fp16.h>
#include <math.h>

typedef _Float16 f16x8 __attribute__((ext_vector_type(8)));
typedef _Float16 f16x4 __attribute__((ext_vector_type(4)));
typedef float f32x4 __attribute__((ext_vector_type(4)));

#define DD     128     // d
#define D2     256     // 2d
#define NB     8192    // batch
#define NCLS   5
#define KSPLIT 8
#define BM     128
#define PPAD   258     // row stride 516B = 129 dw == 1 mod 32 -> conflict-free
#define NSB    36      // 8x8 block-triangle: 28 off-diag (V+V^T) + 8 diag (raw V)
#define SB_BYTES  262144u              // 128 granules * 128 n * 16 B
#define TAIL_OFF  (36u * 262144u)      // W_w tail after all superblocks
#define PART_OFF  (10u * 1048576u)     // fp32 partials at +10 MB

// ---- prep: build symmetrized Vt fp16 in MFMA fragment layout ----------------------------
__global__ void prep_vt(const float* __restrict__ V, const float* __restrict__ Ww,
                        _Float16* __restrict__ Vt) {
    int t = blockIdx.x * 256 + threadIdx.x;      // thread per (granule-unit, n)
    int u = t >> 7;
    int n = t & 127;
    f16x8 v;
    if (u < NSB * 128) {
        int s = u >> 7, g = u & 127;
        int bi = 0, rem = s;
        while (rem >= 8 - bi) { rem -= 8 - bi; ++bi; }
        int bj = bi + rem;
        int i  = bi * 32 + (g >> 2);
        int j0 = bj * 32 + (g & 3) * 8;
        if (bi == bj) {
            #pragma unroll
            for (int e = 0; e < 8; ++e)
                v[e] = (_Float16)V[((size_t)i * 256 + j0 + e) * 128 + n];
        } else {
            #pragma unroll
            for (int e = 0; e < 8; ++e)
                v[e] = (_Float16)(V[((size_t)i * 256 + j0 + e) * 128 + n]
                                + V[((size_t)(j0 + e) * 256 + i) * 128 + n]);
        }
    } else {
        int g = u - NSB * 128;                   // 0..31
        int j0 = g * 8;
        #pragma unroll
        for (int e = 0; e < 8; ++e)
            v[e] = (_Float16)Ww[n * D2 + j0 + e];
    }
    *(f16x8*)(Vt + (size_t)u * 1024 + n * 8) = v;
}

// ---------------- main: tp_partial[ks][b][k] via outer-product-A MFMA GEMM ----------------
// 2x2 wave grid (mr=4, nr=4). DEPTH-6 prefetch: 8 asm-pinned buffers, issue loads for
// cluster c+6 before consuming c under s_waitcnt vmcnt(24). Cover = 6 cluster-periods
// breaks the D=2 equilibrium (P >= L/2 -> 47% util) that capped R5-R15.
__global__ __launch_bounds__(256, 2) void gemm_bilinear(
        const float* __restrict__ left, const float* __restrict__ right,
        const _Float16* __restrict__ Vt, float* __restrict__ part) {
    __shared__ _Float16 P[BM][PPAD];

    const int bid = blockIdx.x;
    const int ks  = bid & 7;       // == XCD id under round-robin dispatch -> slice per XCD L2
    const int m0  = (bid >> 3) * BM;
    const int tid = threadIdx.x;

    // stage phrase tile (fp32 global -> fp16 LDS), coalesced float4 reads
    for (int it = 0; it < 32; ++it) {
        int f4  = it * 256 + tid;          // float4 index over [128][256]
        int row = f4 >> 6;
        int col = (f4 & 63) * 4;
        const float* src = (col < DD) ? (left  + (size_t)(m0 + row) * DD + col)
                                      : (right + (size_t)(m0 + row) * DD + (col - DD));
        float4 x = *(const float4*)src;
        f16x4 hv;
        hv[0] = (_Float16)x.x; hv[1] = (_Float16)x.y;
        hv[2] = (_Float16)x.z; hv[3] = (_Float16)x.w;
        *(f16x4*)&P[row][col] = hv;
    }
    __syncthreads();

    const int lane = tid & 63;
    const int wid  = tid >> 6;
    const int wm   = wid >> 1, wn = wid & 1;   // 2x2 wave grid, 64x64 wave tile
    const int l15  = lane & 15, lg = lane >> 4;
    const int rowb = wm * 64;
    const int coln = wn * 64;

    f32x4 acc[4][4];
    #pragma unroll
    for (int u = 0; u < 4; ++u)
        #pragma unroll
        for (int w = 0; w < 4; ++w)
            acc[u][w] = (f32x4){0.f, 0.f, 0.f, 0.f};

    const unsigned lane_nbyte = (unsigned)((coln + l15) * 16);
    #define LDV(off) (*(const f16x8*)((const char*)Vt + (off)))

    // inline-asm B-load: 4 x dwordx4, saddr form + imm offsets. Pinned issue order.
    #define LOADB(BUF)                                                                    \
        asm volatile("global_load_dwordx4 %0, %4, %5\n\t"                                 \
                     "global_load_dwordx4 %1, %4, %5 offset:256\n\t"                      \
                     "global_load_dwordx4 %2, %4, %5 offset:512\n\t"                      \
                     "global_load_dwordx4 %3, %4, %5 offset:768"                          \
            : "=&v"(BUF[0]), "=&v"(BUF[1]), "=&v"(BUF[2]), "=&v"(BUF[3])                  \
            : "v"(voff), "s"(Vt));                                                        \
        voff += 8192u;

    // counted wait that DEFINES the buffer it guards (dataflow-ordered, nothing else fenced)
    #define WAITN(N, BUF)                                                                 \
        asm volatile("s_waitcnt vmcnt(" #N ")"                                            \
            : "+v"(BUF[0]), "+v"(BUF[1]), "+v"(BUF[2]), "+v"(BUF[3]));

    #define MFMA_CLUSTER(BUF, IBE)                                                        \
        _Pragma("unroll")                                                                 \
        for (int mr = 0; mr < 4; ++mr) {                                                  \
            const _Float16 sc = pis[mr][IBE];                                             \
            const f16x8 a = pj[mr] * sc;                                                  \
            _Pragma("unroll")                                                             \
            for (int nr = 0; nr < 4; ++nr)                                                \
                acc[mr][nr] = __builtin_amdgcn_mfma_f32_16x16x32_f16(a, BUF[nr], acc[mr][nr], 0, 0, 0); \
        }

    #define LOAD_PIS(IBC)                                                                 \
        f16x8 pis[4];                                                                     \
        _Pragma("unroll")                                                                 \
        for (int mr = 0; mr < 4; ++mr)                                                    \
            pis[mr] = *(const f16x8*)&P[rowb + mr * 16 + l15][bi * 32 + (IBC) * 8];

    #pragma unroll 1
    for (int si = 0; si < 5; ++si) {
        int s, ibcS, ibcE;
        if (si < 4) { s = ks * 4 + si;      ibcS = 0;            ibcE = 4; }
        else        { s = 32 + (ks >> 1);   ibcS = (ks & 1) * 2; ibcE = ibcS + 2; }

        // decode (bi, bj) from triangle slot (wave-uniform scalar loop)
        int bi = 0, rem = s;
        while (rem >= 8 - bi) { rem -= 8 - bi; ++bi; }
        const int bj = bi + rem;

        // A j-fragments for this superblock (invariant over i)
        f16x8 pj[4];
        #pragma unroll
        for (int mr = 0; mr < 4; ++mr)
            pj[mr] = *(const f16x8*)&P[rowb + mr * 16 + l15][bj * 32 + lg * 8];

        unsigned voff = lane_nbyte + (unsigned)s * SB_BYTES + (unsigned)(lg * 2048)
                      + (unsigned)(ibcS * 65536);

        // prologue: fill pipeline to depth 6 (clusters 0..5 of this superblock)
        f16x8 B0[4], B1[4], B2[4], B3[4], B4[4], B5[4], B6[4], B7[4];
        LOADB(B0) LOADB(B1) LOADB(B2) LOADB(B3) LOADB(B4) LOADB(B5)

        // steady ibcs (all but the last of this superblock):
        // step c: issue loads for c+6 into B[(c+6)%8], wait vmcnt(24), consume B[c%8]
        #pragma unroll 1
        for (int ibc = ibcS; ibc < ibcE - 1; ++ibc) {
            LOAD_PIS(ibc)
            LOADB(B6)  WAITN(24, B0)  MFMA_CLUSTER(B0, 0)
            LOADB(B7)  WAITN(24, B1)  MFMA_CLUSTER(B1, 1)
            LOADB(B0)  WAITN(24, B2)  MFMA_CLUSTER(B2, 2)
            LOADB(B1)  WAITN(24, B3)  MFMA_CLUSTER(B3, 3)
            LOADB(B2)  WAITN(24, B4)  MFMA_CLUSTER(B4, 4)
            LOADB(B3)  WAITN(24, B5)  MFMA_CLUSTER(B5, 5)
            LOADB(B4)  WAITN(24, B6)  MFMA_CLUSTER(B6, 6)
            LOADB(B5)  WAITN(24, B7)  MFMA_CLUSTER(B7, 7)
        }

        // final ibc: steps 0,1 issue the last in-superblock targets; steps 2-7 drain
        // 20->0. Every def consumed before any register reuse -> no R11 hazard.
        {
            LOAD_PIS(ibcE - 1)
            LOADB(B6)  WAITN(24, B0)  MFMA_CLUSTER(B0, 0)
            LOADB(B7)  WAITN(24, B1)  MFMA_CLUSTER(B1, 1)
                       WAITN(20, B2)  MFMA_CLUSTER(B2, 2)
                       WAITN(16, B3)  MFMA_CLUSTER(B3, 3)
                       WAITN(12, B4)  MFMA_CLUSTER(B4, 4)
                       WAITN(8,  B5)  MFMA_CLUSTER(B5, 5)
                       WAITN(4,  B6)  MFMA_CLUSTER(B6, 6)
                       WAITN(0,  B7)  MFMA_CLUSTER(B7, 7)
        }
    }

    // last split also does the folded W_w matvec tail: A = P directly
    if (ks == KSPLIT - 1) {
        #pragma unroll 1
        for (int jc = 0; jc < 8; ++jc) {
            unsigned voff = TAIL_OFF + (unsigned)((jc * 4 + lg) * 2048) + lane_nbyte;
            f16x8 bfr[4];
            #pragma unroll
            for (int nr = 0; nr < 4; ++nr) bfr[nr] = LDV(voff + nr * 256);
            #pragma unroll
            for (int mr = 0; mr < 4; ++mr) {
                const f16x8 a = *(const f16x8*)&P[rowb + mr * 16 + l15][jc * 32 + lg * 8];
                #pragma unroll
                for (int nr = 0; nr < 4; ++nr)
                    acc[mr][nr] = __builtin_amdgcn_mfma_f32_16x16x32_f16(a, bfr[nr], acc[mr][nr], 0, 0, 0);
            }
        }
    }

    // write fp32 partials; C/D layout: col = lane&15, row = (lane>>4)*4 + q  [m89-verified]
    float* base = part + ((size_t)ks * NB + m0) * DD;
    #pragma unroll
    for (int mr = 0; mr < 4; ++mr)
        #pragma unroll
        for (int nr = 0; nr < 4; ++nr) {
            const int col = coln + nr * 16 + l15;
            #pragma unroll
            for (int q = 0; q < 4; ++q) {
                const int row = rowb + mr * 16 + lg * 4 + q;
                base[(size_t)row * DD + col] = acc[mr][nr][q];
            }
        }
}

// ---------------- epilogue: reduce splits, +W_b, tanh, 5-class logits, log_softmax --------
// 8 threads per batch row (k-split 16 each) + shuffle reduce
__global__ void finish(const float* __restrict__ part, const float* __restrict__ Wb,
                       const float* __restrict__ Wsw, const float* __restrict__ Wsb,
                       float* __restrict__ out) {
    int t  = blockIdx.x * 256 + threadIdx.x;
    int b  = t >> 3;
    int kq = t & 7;                 // k-eighth
    if (b >= NB) return;
    float lg[NCLS];
    #pragma unroll
    for (int c = 0; c < NCLS; ++c) lg[c] = 0.f;

    const float* pb = part + (size_t)b * DD + kq * 16;
    #pragma unroll 1
    for (int k4 = 0; k4 < 4; ++k4) {
        float4 tt = *(const float4*)(Wb + kq * 16 + k4 * 4);
        #pragma unroll
        for (int s = 0; s < KSPLIT; ++s) {
            float4 p = *(const float4*)(pb + (size_t)s * NB * DD + k4 * 4);
            tt.x += p.x; tt.y += p.y; tt.z += p.z; tt.w += p.w;
        }
        float tq[4] = {tt.x, tt.y, tt.z, tt.w};
        #pragma unroll
        for (int q = 0; q < 4; ++q) {
            float h = tanhf(tq[q]);
            int k = kq * 16 + k4 * 4 + q;
            #pragma unroll
            for (int c = 0; c < NCLS; ++c)
                lg[c] += h * Wsw[c * DD + k];
        }
    }
    // reduce across the 8 k-eighth lanes (lane bits 0..2)
    #pragma unroll
    for (int c = 0; c < NCLS; ++c) {
        lg[c] += __shfl_xor(lg[c], 1);
        lg[c] += __shfl_xor(lg[c], 2);
        lg[c] += __shfl_xor(lg[c], 4);
    }
    if (kq == 0) {
        #pragma unroll
        for (int c = 0; c < NCLS; ++c) lg[c] += Wsb[c];
        float mx = lg[0];
        #pragma unroll
        for (int c = 1; c < NCLS; ++c) mx = fmaxf(mx, lg[c]);
        float sum = 0.f;
        #pragma unroll
        for (int c = 0; c < NCLS; ++c) sum += expf(lg[c] - mx);
        float lse = logf(sum);
        #pragma unroll
        for (int c = 0; c < NCLS; ++c) out[b * NCLS + c] = lg[c] - mx - lse;
    }
}

extern "C" void kernel_launch(void* const* d_in, const int* in_sizes, int n_in,
                              void* d_out, int out_size, void* d_ws, size_t ws_size,
                              hipStream_t stream) {
    const float* left  = (const float*)d_in[0];
    const float* right = (const float*)d_in[1];
    const float* V     = (const float*)d_in[2];
    const float* Ww    = (const float*)d_in[3];
    const float* Wb    = (const float*)d_in[4];
    const float* Wsw   = (const float*)d_in[5];
    const float* Wsb   = (const float*)d_in[6];
    float* out = (float*)d_out;

    _Float16* Vt = (_Float16*)d_ws;                       // 9,502,720 B incl. tail
    float* part  = (float*)((char*)d_ws + PART_OFF);      // 33,554,432 B

    hipLaunchKernelGGL(prep_vt, dim3(2320), dim3(256), 0, stream, V, Ww, Vt);
    hipLaunchKernelGGL(gemm_bilinear, dim3((NB / BM) * KSPLIT), dim3(256), 0, stream,
                       left, right, Vt, part);
    hipLaunchKernelGGL(finish, dim3(NB * 8 / 256), dim3(256), 0, stream, part, Wb, Wsw, Wsb, out);
}